// Round 1
// baseline (344.630 us; speedup 1.0000x reference)
//
#include <hip/hip_runtime.h>
#include <stdint.h>

#define B_ 4
#define T_ 4096
#define C_ 1024
#define H_ 128

typedef __attribute__((ext_vector_type(8))) short s16x8;   // 8 bf16 (4 VGPRs)
typedef __attribute__((ext_vector_type(4))) float f32x4;   // MFMA accumulator

__device__ __forceinline__ unsigned short f2bf(float f) {
    union { float f; unsigned u; } v; v.f = f;
    unsigned r = v.u + 0x7fffu + ((v.u >> 16) & 1u);
    return (unsigned short)(r >> 16);
}

__device__ __forceinline__ s16x8 as_frag(uint4 u) {
    union { uint4 u; s16x8 s; } v; v.u = u; return v.s;
}

// ---------------------------------------------------------------------------
// Kernel 1: W [1024][128] fp32 -> Wt [3*128][1024] bf16 (transposed, converted)
// ---------------------------------------------------------------------------
__global__ __launch_bounds__(256) void k_wt(const float* __restrict__ Wk,
                                            const float* __restrict__ Wq,
                                            const float* __restrict__ Wv,
                                            unsigned short* __restrict__ Wt) {
    __shared__ float tile[64][65];  // +1 pad breaks bank conflicts on transpose
    int w = blockIdx.z;  // 0=K, 1=Q, 2=V  (matches input order Wk,Wq,Wv)
    const float* W = (w == 0) ? Wk : (w == 1) ? Wq : Wv;
    int c0 = blockIdx.x * 64, h0 = blockIdx.y * 64;
    int tid = threadIdx.x;
#pragma unroll
    for (int k = 0; k < 16; k++) {
        int idx = tid + k * 256;
        int r = idx >> 6, c = idx & 63;              // r: C-dim, c: H-dim
        tile[r][c] = W[(size_t)(c0 + r) * H_ + h0 + c];
    }
    __syncthreads();
#pragma unroll
    for (int k = 0; k < 16; k++) {
        int idx = tid + k * 256;
        int hh = idx >> 6, cc = idx & 63;
        Wt[(size_t)(w * H_ + h0 + hh) * C_ + c0 + cc] = f2bf(tile[cc][hh]);
    }
}

// ---------------------------------------------------------------------------
// Kernel 2: fused QKV GEMM.  x[16384][1024] fp32 @ Wt[384][1024] bf16(T)
//   -> Qb,Kb [16384][128] bf16 ; Vt [4][128][4096] bf16 (transposed)
// Block: 64 rows, 4 waves; wave owns 96 cols (6 n-tiles). A staged in LDS.
// ---------------------------------------------------------------------------
__global__ __launch_bounds__(256) void k_qkv(const float* __restrict__ x,
                                             const unsigned short* __restrict__ Wt,
                                             unsigned short* __restrict__ Qb,
                                             unsigned short* __restrict__ Kb,
                                             unsigned short* __restrict__ Vt) {
    __shared__ unsigned short a_lds[64 * 40];  // 64 rows x 32 k, stride 40 (pad 8)
    int tid = threadIdx.x;
    int wv = tid >> 6, lane = tid & 63, quad = lane >> 4, lo = lane & 15;
    int r0 = blockIdx.x * 64;
    int nt0 = wv * 6;

    f32x4 acc[6][4];
#pragma unroll
    for (int i = 0; i < 6; i++)
#pragma unroll
        for (int j = 0; j < 4; j++) acc[i][j] = (f32x4){0.f, 0.f, 0.f, 0.f};

    const int row_s = tid >> 2;   // 0..63
    const int seg_s = tid & 3;    // 0..3 (8 floats each)
    size_t xbase = (size_t)(r0 + row_s) * C_ + seg_s * 8;

    for (int sl = 0; sl < 32; sl++) {
        float4 f0 = *(const float4*)(x + xbase + sl * 32);
        float4 f1 = *(const float4*)(x + xbase + sl * 32 + 4);
        uint4 pk;
        pk.x = (unsigned)f2bf(f0.x) | ((unsigned)f2bf(f0.y) << 16);
        pk.y = (unsigned)f2bf(f0.z) | ((unsigned)f2bf(f0.w) << 16);
        pk.z = (unsigned)f2bf(f1.x) | ((unsigned)f2bf(f1.y) << 16);
        pk.w = (unsigned)f2bf(f1.z) | ((unsigned)f2bf(f1.w) << 16);
        *(uint4*)&a_lds[row_s * 40 + seg_s * 8] = pk;
        __syncthreads();

        s16x8 a_frag[4];
#pragma unroll
        for (int mt = 0; mt < 4; mt++)
            a_frag[mt] = *(const s16x8*)&a_lds[(mt * 16 + lo) * 40 + quad * 8];
#pragma unroll
        for (int nt = 0; nt < 6; nt++) {
            s16x8 b = *(const s16x8*)(Wt + (size_t)((nt0 + nt) * 16 + lo) * C_ + sl * 32 + quad * 8);
#pragma unroll
            for (int mt = 0; mt < 4; mt++)
                acc[nt][mt] = __builtin_amdgcn_mfma_f32_16x16x32_bf16(
                    a_frag[mt], b, acc[nt][mt], 0, 0, 0);
        }
        __syncthreads();
    }

    // Epilogue. C-layout: row = mt*16 + quad*4 + r, col = (nt0+nt)*16 + lo
#pragma unroll
    for (int nt = 0; nt < 6; nt++) {
        int col = (nt0 + nt) * 16 + lo;
        int w = col >> 7, h = col & 127;
#pragma unroll
        for (int mt = 0; mt < 4; mt++) {
            int mrow = r0 + mt * 16 + quad * 4;  // + r
            if (w == 2) {
                // V transposed: Vt[b][h][t], pack 4 consecutive t
                int b = mrow >> 12, t = mrow & 4095;
                uint2 pk;
                pk.x = (unsigned)f2bf(acc[nt][mt][0]) | ((unsigned)f2bf(acc[nt][mt][1]) << 16);
                pk.y = (unsigned)f2bf(acc[nt][mt][2]) | ((unsigned)f2bf(acc[nt][mt][3]) << 16);
                *(uint2*)(Vt + (size_t)(b * H_ + h) * T_ + t) = pk;
            } else {
                unsigned short* dst = (w == 0 ? Kb : Qb) + (size_t)mrow * H_ + h;
#pragma unroll
                for (int r = 0; r < 4; r++)
                    dst[(size_t)r * H_] = f2bf(acc[nt][mt][r]);
            }
        }
    }
}

// ---------------------------------------------------------------------------
// Kernel 3: causal flash attention.  Block = 64-row Q tile, 4 waves x 16 rows.
// K/Vt tiles (64 keys) staged in LDS (XOR swizzle, 16B granule).
// ---------------------------------------------------------------------------
__global__ __launch_bounds__(256) void k_attn(const unsigned short* __restrict__ Qb,
                                              const unsigned short* __restrict__ Kb,
                                              const unsigned short* __restrict__ Vt,
                                              float* __restrict__ out) {
    __shared__ uint4 kbuf[64 * 16];               // 64 keys x 128 dim bf16
    __shared__ uint4 vbuf[128 * 8];               // 128 dim x 64 keys bf16 (from Vt)
    __shared__ unsigned short pbuf[4][16 * 64];   // per-wave P transpose buffer

    int tid = threadIdx.x;
    int wv = tid >> 6, lane = tid & 63, quad = lane >> 4, lo = lane & 15;
    int batch = blockIdx.x >> 6, qt = blockIdx.x & 63;
    int qr0 = qt * 64;
    int m0 = qr0 + wv * 16;  // wave's first query row (within batch)

    // Q fragments, resident for the whole kernel
    s16x8 qf[4];
    size_t qrow = (size_t)(batch * T_ + m0 + lo) * H_;
#pragma unroll
    for (int ks = 0; ks < 4; ks++)
        qf[ks] = *(const s16x8*)(Qb + qrow + ks * 32 + quad * 8);

    f32x4 acc_o[8];
#pragma unroll
    for (int o = 0; o < 8; o++) acc_o[o] = (f32x4){0.f, 0.f, 0.f, 0.f};
    float m_i[4], l_i[4];
#pragma unroll
    for (int r = 0; r < 4; r++) { m_i[r] = -INFINITY; l_i[r] = 0.f; }

    const float kscale = 0.0883883476f * 1.4426950408f;  // 1/sqrt(128) * log2(e)

    const int srow_k = tid >> 2, sseg_k = (tid & 3) * 4;   // K stage: 4 thr/row
    const int srow_v = tid >> 1, sseg_v = (tid & 1) * 4;   // V stage: 2 thr/row

    for (int t = 0; t <= qt; t++) {
        int kv0 = t * 64;
        // ---- stage K tile ----
        const uint4* kg = (const uint4*)(Kb + (size_t)(batch * T_ + kv0 + srow_k) * H_);
#pragma unroll
        for (int i = 0; i < 4; i++) {
            int s = sseg_k + i;
            kbuf[srow_k * 16 + (s ^ (srow_k & 15))] = kg[s];
        }
        // ---- stage V tile (from Vt, rows = head dims) ----
        const uint4* vg = (const uint4*)(Vt + (size_t)(batch * H_ + srow_v) * T_ + kv0);
#pragma unroll
        for (int i = 0; i < 4; i++) {
            int s = sseg_v + i;
            vbuf[srow_v * 8 + (s ^ (srow_v & 7))] = vg[s];
        }
        __syncthreads();

        // ---- S = Q K^T (16 rows x 64 keys per wave) ----
        f32x4 s_acc[4];
#pragma unroll
        for (int nt = 0; nt < 4; nt++) s_acc[nt] = (f32x4){0.f, 0.f, 0.f, 0.f};
#pragma unroll
        for (int ks = 0; ks < 4; ks++) {
#pragma unroll
            for (int nt = 0; nt < 4; nt++) {
                s16x8 kf = as_frag(kbuf[(nt * 16 + lo) * 16 + ((ks * 4 + quad) ^ lo)]);
                s_acc[nt] = __builtin_amdgcn_mfma_f32_16x16x32_bf16(qf[ks], kf, s_acc[nt], 0, 0, 0);
            }
        }

        // ---- online softmax (exp2 domain) ----
        float p[4][4];
        bool diag = (t == qt);
#pragma unroll
        for (int nt = 0; nt < 4; nt++)
#pragma unroll
            for (int r = 0; r < 4; r++) {
                float sv = s_acc[nt][r] * kscale;
                if (diag) {
                    int colg = kv0 + nt * 16 + lo;
                    int rowg = m0 + quad * 4 + r;
                    if (colg > rowg) sv = -INFINITY;
                }
                p[nt][r] = sv;
            }
        float mnew[4], alpha[4];
#pragma unroll
        for (int r = 0; r < 4; r++) {
            float mx = fmaxf(fmaxf(p[0][r], p[1][r]), fmaxf(p[2][r], p[3][r]));
            mx = fmaxf(mx, __shfl_xor(mx, 1));
            mx = fmaxf(mx, __shfl_xor(mx, 2));
            mx = fmaxf(mx, __shfl_xor(mx, 4));
            mx = fmaxf(mx, __shfl_xor(mx, 8));
            mnew[r] = fmaxf(m_i[r], mx);
            alpha[r] = exp2f(m_i[r] - mnew[r]);
            m_i[r] = mnew[r];
        }
        float rs[4] = {0.f, 0.f, 0.f, 0.f};
#pragma unroll
        for (int nt = 0; nt < 4; nt++)
#pragma unroll
            for (int r = 0; r < 4; r++) {
                float pv = exp2f(p[nt][r] - mnew[r]);
                p[nt][r] = pv;
                rs[r] += pv;
            }
#pragma unroll
        for (int r = 0; r < 4; r++) {
            rs[r] += __shfl_xor(rs[r], 1);
            rs[r] += __shfl_xor(rs[r], 2);
            rs[r] += __shfl_xor(rs[r], 4);
            rs[r] += __shfl_xor(rs[r], 8);
            l_i[r] = l_i[r] * alpha[r] + rs[r];
        }
#pragma unroll
        for (int o = 0; o < 8; o++)
#pragma unroll
            for (int r = 0; r < 4; r++) acc_o[o][r] *= alpha[r];

        // ---- P: C-layout -> A-layout via per-wave LDS ----
        unsigned short* pb = pbuf[wv];
#pragma unroll
        for (int nt = 0; nt < 4; nt++)
#pragma unroll
            for (int r = 0; r < 4; r++) {
                int prow = quad * 4 + r;
                int col = nt * 16 + lo;
                int seg = col >> 3, off = col & 7;
                pb[prow * 64 + ((seg ^ (prow & 7)) << 3) + off] = f2bf(p[nt][r]);
            }
        s16x8 pf[2];
#pragma unroll
        for (int kss = 0; kss < 2; kss++) {
            int seg = kss * 4 + quad;
            pf[kss] = *(const s16x8*)&pb[lo * 64 + ((seg ^ (lo & 7)) << 3)];
        }

        // ---- O += P V ----
#pragma unroll
        for (int kss = 0; kss < 2; kss++)
#pragma unroll
            for (int o = 0; o < 8; o++) {
                int vrow = o * 16 + lo;
                s16x8 vf = as_frag(vbuf[vrow * 8 + ((kss * 4 + quad) ^ (vrow & 7))]);
                acc_o[o] = __builtin_amdgcn_mfma_f32_16x16x32_bf16(pf[kss], vf, acc_o[o], 0, 0, 0);
            }
        __syncthreads();  // protect kbuf/vbuf before next stage
    }

    // ---- epilogue: normalize and store fp32 ----
    float inv[4];
#pragma unroll
    for (int r = 0; r < 4; r++) inv[r] = 1.0f / l_i[r];
#pragma unroll
    for (int o = 0; o < 8; o++)
#pragma unroll
        for (int r = 0; r < 4; r++) {
            int rowg = batch * T_ + m0 + quad * 4 + r;
            out[(size_t)rowg * H_ + o * 16 + lo] = acc_o[o][r] * inv[r];
        }
}

// ---------------------------------------------------------------------------
extern "C" void kernel_launch(void* const* d_in, const int* in_sizes, int n_in,
                              void* d_out, int out_size, void* d_ws, size_t ws_size,
                              hipStream_t stream) {
    const float* x  = (const float*)d_in[0];
    const float* Wk = (const float*)d_in[1];
    const float* Wq = (const float*)d_in[2];
    const float* Wv = (const float*)d_in[3];
    char* ws = (char*)d_ws;
    unsigned short* Wt = (unsigned short*)ws;                          // 768 KB
    unsigned short* Qb = (unsigned short*)(ws + (1u << 20));           // 4 MB
    unsigned short* Kb = (unsigned short*)(ws + (1u << 20) + (4u << 20));
    unsigned short* Vt = (unsigned short*)(ws + (1u << 20) + (8u << 20));
    float* out = (float*)d_out;

    k_wt  <<<dim3(16, 2, 3), 256, 0, stream>>>(Wk, Wq, Wv, Wt);
    k_qkv <<<256, 256, 0, stream>>>(x, Wt, Qb, Kb, Vt);
    k_attn<<<256, 256, 0, stream>>>(Qb, Kb, Vt, out);
}

// Round 2
// 215.759 us; speedup vs baseline: 1.5973x; 1.5973x over previous
//
#include <hip/hip_runtime.h>
#include <stdint.h>
#include <math.h>

#define B_ 4
#define T_ 4096
#define C_ 1024
#define H_ 128

typedef __attribute__((ext_vector_type(8))) short s16x8;   // 8 bf16 (4 VGPRs)
typedef __attribute__((ext_vector_type(4))) float f32x4;   // MFMA accumulator

__device__ __forceinline__ unsigned short f2bf(float f) {
    union { float f; unsigned u; } v; v.f = f;
    unsigned r = v.u + 0x7fffu + ((v.u >> 16) & 1u);
    return (unsigned short)(r >> 16);
}

__device__ __forceinline__ s16x8 as_frag(uint4 u) {
    union { uint4 u; s16x8 s; } v; v.u = u; return v.s;
}

// softmax scale folded into Q at projection time: 1/sqrt(128) * log2(e)
#define QSC (0.0883883476f * 1.4426950408f)

// ---------------------------------------------------------------------------
// Kernel 1: W [1024][128] fp32 -> Wt [3*128][1024] bf16 (transposed, converted)
// ---------------------------------------------------------------------------
__global__ __launch_bounds__(256) void k_wt(const float* __restrict__ Wk,
                                            const float* __restrict__ Wq,
                                            const float* __restrict__ Wv,
                                            unsigned short* __restrict__ Wt) {
    __shared__ float tile[64][65];
    int w = blockIdx.z;  // 0=K, 1=Q, 2=V
    const float* W = (w == 0) ? Wk : (w == 1) ? Wq : Wv;
    int c0 = blockIdx.x * 64, h0 = blockIdx.y * 64;
    int tid = threadIdx.x;
#pragma unroll
    for (int k = 0; k < 16; k++) {
        int idx = tid + k * 256;
        int r = idx >> 6, c = idx & 63;
        tile[r][c] = W[(size_t)(c0 + r) * H_ + h0 + c];
    }
    __syncthreads();
#pragma unroll
    for (int k = 0; k < 16; k++) {
        int idx = tid + k * 256;
        int hh = idx >> 6, cc = idx & 63;
        Wt[(size_t)(w * H_ + h0 + hh) * C_ + c0 + cc] = f2bf(tile[cc][hh]);
    }
}

// ---------------------------------------------------------------------------
// Kernel 2: fused QKV GEMM.  512 blocks: 256 row-tiles (64 rows) x 2 col-halves
// (192 cols). Wave owns 48 cols x 64 rows. K-chunk = 64 (16 barrier pairs).
// Q is pre-scaled by QSC at write. V written transposed: Vt[b][h][t].
// ---------------------------------------------------------------------------
__global__ __launch_bounds__(256) void k_qkv(const float* __restrict__ x,
                                             const unsigned short* __restrict__ Wt,
                                             unsigned short* __restrict__ Qb,
                                             unsigned short* __restrict__ Kb,
                                             unsigned short* __restrict__ Vt) {
    __shared__ unsigned short a_lds[64 * 72];  // 64 rows x 64 k, stride 72 (16B-aligned rows)
    int tid = threadIdx.x;
    int wv = tid >> 6, lane = tid & 63, quad = lane >> 4, lo = lane & 15;
    int r0 = blockIdx.x * 64;
    int cb = blockIdx.y;          // col half: cols [cb*192, cb*192+192)
    int nt0 = wv * 3;

    f32x4 acc[3][4];
#pragma unroll
    for (int i = 0; i < 3; i++)
#pragma unroll
        for (int j = 0; j < 4; j++) acc[i][j] = (f32x4){0.f, 0.f, 0.f, 0.f};

    const int row_s = tid >> 2;        // 0..63
    const int seg_s = (tid & 3) * 16;  // float offset within row
    size_t xbase = (size_t)(r0 + row_s) * C_ + seg_s;

    for (int kc = 0; kc < 16; kc++) {
        const float* xp = x + xbase + kc * 64;
        float4 f0 = *(const float4*)(xp);
        float4 f1 = *(const float4*)(xp + 4);
        float4 f2 = *(const float4*)(xp + 8);
        float4 f3 = *(const float4*)(xp + 12);
        uint4 u0, u1;
        u0.x = (unsigned)f2bf(f0.x) | ((unsigned)f2bf(f0.y) << 16);
        u0.y = (unsigned)f2bf(f0.z) | ((unsigned)f2bf(f0.w) << 16);
        u0.z = (unsigned)f2bf(f1.x) | ((unsigned)f2bf(f1.y) << 16);
        u0.w = (unsigned)f2bf(f1.z) | ((unsigned)f2bf(f1.w) << 16);
        u1.x = (unsigned)f2bf(f2.x) | ((unsigned)f2bf(f2.y) << 16);
        u1.y = (unsigned)f2bf(f2.z) | ((unsigned)f2bf(f2.w) << 16);
        u1.z = (unsigned)f2bf(f3.x) | ((unsigned)f2bf(f3.y) << 16);
        u1.w = (unsigned)f2bf(f3.z) | ((unsigned)f2bf(f3.w) << 16);
        *(uint4*)&a_lds[row_s * 72 + seg_s] = u0;
        *(uint4*)&a_lds[row_s * 72 + seg_s + 8] = u1;
        __syncthreads();

        s16x8 a_frag[4][2];
#pragma unroll
        for (int mt = 0; mt < 4; mt++)
#pragma unroll
            for (int kh = 0; kh < 2; kh++)
                a_frag[mt][kh] = *(const s16x8*)&a_lds[(mt * 16 + lo) * 72 + kh * 32 + quad * 8];
#pragma unroll
        for (int nt = 0; nt < 3; nt++) {
            int gcol = cb * 192 + (nt0 + nt) * 16 + lo;
#pragma unroll
            for (int kh = 0; kh < 2; kh++) {
                s16x8 b = *(const s16x8*)(Wt + (size_t)gcol * C_ + kc * 64 + kh * 32 + quad * 8);
#pragma unroll
                for (int mt = 0; mt < 4; mt++)
                    acc[nt][mt] = __builtin_amdgcn_mfma_f32_16x16x32_bf16(
                        a_frag[mt][kh], b, acc[nt][mt], 0, 0, 0);
            }
        }
        __syncthreads();
    }

    // Epilogue. C-layout: row = mt*16 + quad*4 + r, col = cb*192 + (nt0+nt)*16 + lo
#pragma unroll
    for (int nt = 0; nt < 3; nt++) {
        int col = cb * 192 + (nt0 + nt) * 16 + lo;
        int w = col >> 7, h = col & 127;
#pragma unroll
        for (int mt = 0; mt < 4; mt++) {
            int mrow = r0 + mt * 16 + quad * 4;
            if (w == 2) {
                int b = mrow >> 12, t = mrow & 4095;
                uint2 pk;
                pk.x = (unsigned)f2bf(acc[nt][mt][0]) | ((unsigned)f2bf(acc[nt][mt][1]) << 16);
                pk.y = (unsigned)f2bf(acc[nt][mt][2]) | ((unsigned)f2bf(acc[nt][mt][3]) << 16);
                *(uint2*)(Vt + (size_t)(b * H_ + h) * T_ + t) = pk;
            } else if (w == 1) {
                unsigned short* dst = Qb + (size_t)mrow * H_ + h;
#pragma unroll
                for (int r = 0; r < 4; r++)
                    dst[(size_t)r * H_] = f2bf(acc[nt][mt][r] * QSC);
            } else {
                unsigned short* dst = Kb + (size_t)mrow * H_ + h;
#pragma unroll
                for (int r = 0; r < 4; r++)
                    dst[(size_t)r * H_] = f2bf(acc[nt][mt][r]);
            }
        }
    }
}

// ---------------------------------------------------------------------------
// Kernel 3: causal flash attention with split-KV.
// Grid = 64 qtiles * 4 batches * NSPLIT, largest q-tile first.
// Block = 64 q-rows, 4 waves x 16 rows; processes KV tiles t = split, split+NS,...
// NSPLIT>1: writes unnormalized O (fp32) + m,l per row to workspace.
// ---------------------------------------------------------------------------
template <int NSPLIT>
__global__ __launch_bounds__(256, 4) void k_attn(const unsigned short* __restrict__ Qb,
                                                 const unsigned short* __restrict__ Kb,
                                                 const unsigned short* __restrict__ Vt,
                                                 float* __restrict__ Opart,
                                                 float* __restrict__ Mpart,
                                                 float* __restrict__ Lpart,
                                                 float* __restrict__ out) {
    __shared__ uint4 kbuf[64 * 16];
    __shared__ uint4 vbuf[128 * 8];
    __shared__ unsigned short pbuf[4][16 * 64];

    int tid = threadIdx.x;
    int wv = tid >> 6, lane = tid & 63, quad = lane >> 4, lo = lane & 15;

    int id = blockIdx.x;
    int qt = 63 - id / (4 * NSPLIT);   // largest-first
    int rem = id % (4 * NSPLIT);
    int batch = rem / NSPLIT;
    int split = rem % NSPLIT;
    int m0 = qt * 64 + wv * 16;

    s16x8 qf[4];
    size_t qrow = (size_t)(batch * T_ + m0 + lo) * H_;
#pragma unroll
    for (int ks = 0; ks < 4; ks++)
        qf[ks] = *(const s16x8*)(Qb + qrow + ks * 32 + quad * 8);

    f32x4 acc_o[8];
#pragma unroll
    for (int o = 0; o < 8; o++) acc_o[o] = (f32x4){0.f, 0.f, 0.f, 0.f};
    float m_i[4], l_i[4];
#pragma unroll
    for (int r = 0; r < 4; r++) { m_i[r] = -INFINITY; l_i[r] = 0.f; }

    const int srow_k = tid >> 2, sseg_k = (tid & 3) * 4;
    const int srow_v = tid >> 1, sseg_v = (tid & 1) * 4;

    for (int t = split; t <= qt; t += NSPLIT) {
        int kv0 = t * 64;
        const uint4* kg = (const uint4*)(Kb + (size_t)(batch * T_ + kv0 + srow_k) * H_);
#pragma unroll
        for (int i = 0; i < 4; i++) {
            int s = sseg_k + i;
            kbuf[srow_k * 16 + (s ^ (srow_k & 15))] = kg[s];
        }
        const uint4* vg = (const uint4*)(Vt + (size_t)(batch * H_ + srow_v) * T_ + kv0);
#pragma unroll
        for (int i = 0; i < 4; i++) {
            int s = sseg_v + i;
            vbuf[srow_v * 8 + (s ^ (srow_v & 7))] = vg[s];
        }
        __syncthreads();

        // S = Q K^T, logits already in log2 domain (Q pre-scaled)
        f32x4 s_acc[4];
#pragma unroll
        for (int nt = 0; nt < 4; nt++) s_acc[nt] = (f32x4){0.f, 0.f, 0.f, 0.f};
#pragma unroll
        for (int ks = 0; ks < 4; ks++) {
#pragma unroll
            for (int nt = 0; nt < 4; nt++) {
                s16x8 kf = as_frag(kbuf[(nt * 16 + lo) * 16 + ((ks * 4 + quad) ^ lo)]);
                s_acc[nt] = __builtin_amdgcn_mfma_f32_16x16x32_bf16(qf[ks], kf, s_acc[nt], 0, 0, 0);
            }
        }

        float p[4][4];
        bool diag = (t == qt);
#pragma unroll
        for (int nt = 0; nt < 4; nt++)
#pragma unroll
            for (int r = 0; r < 4; r++) {
                float sv = s_acc[nt][r];
                if (diag) {
                    int colg = kv0 + nt * 16 + lo;
                    int rowg = m0 + quad * 4 + r;
                    if (colg > rowg) sv = -INFINITY;
                }
                p[nt][r] = sv;
            }
        float mnew[4], alpha[4];
#pragma unroll
        for (int r = 0; r < 4; r++) {
            float mx = fmaxf(fmaxf(p[0][r], p[1][r]), fmaxf(p[2][r], p[3][r]));
            mx = fmaxf(mx, __shfl_xor(mx, 1));
            mx = fmaxf(mx, __shfl_xor(mx, 2));
            mx = fmaxf(mx, __shfl_xor(mx, 4));
            mx = fmaxf(mx, __shfl_xor(mx, 8));
            mnew[r] = fmaxf(m_i[r], mx);
            alpha[r] = exp2f(m_i[r] - mnew[r]);
            m_i[r] = mnew[r];
        }
        float rs[4] = {0.f, 0.f, 0.f, 0.f};
#pragma unroll
        for (int nt = 0; nt < 4; nt++)
#pragma unroll
            for (int r = 0; r < 4; r++) {
                float pv = exp2f(p[nt][r] - mnew[r]);
                p[nt][r] = pv;
                rs[r] += pv;
            }
#pragma unroll
        for (int r = 0; r < 4; r++) {
            rs[r] += __shfl_xor(rs[r], 1);
            rs[r] += __shfl_xor(rs[r], 2);
            rs[r] += __shfl_xor(rs[r], 4);
            rs[r] += __shfl_xor(rs[r], 8);
            l_i[r] = l_i[r] * alpha[r] + rs[r];
        }
#pragma unroll
        for (int o = 0; o < 8; o++)
#pragma unroll
            for (int r = 0; r < 4; r++) acc_o[o][r] *= alpha[r];

        // P: C-layout -> A-layout via per-wave LDS
        unsigned short* pb = pbuf[wv];
#pragma unroll
        for (int nt = 0; nt < 4; nt++)
#pragma unroll
            for (int r = 0; r < 4; r++) {
                int prow = quad * 4 + r;
                int col = nt * 16 + lo;
                int seg = col >> 3, off = col & 7;
                pb[prow * 64 + ((seg ^ (prow & 7)) << 3) + off] = f2bf(p[nt][r]);
            }
        s16x8 pf[2];
#pragma unroll
        for (int kss = 0; kss < 2; kss++) {
            int seg = kss * 4 + quad;
            pf[kss] = *(const s16x8*)&pb[lo * 64 + ((seg ^ (lo & 7)) << 3)];
        }

#pragma unroll
        for (int kss = 0; kss < 2; kss++)
#pragma unroll
            for (int o = 0; o < 8; o++) {
                int vrow = o * 16 + lo;
                s16x8 vf = as_frag(vbuf[vrow * 8 + ((kss * 4 + quad) ^ (vrow & 7))]);
                acc_o[o] = __builtin_amdgcn_mfma_f32_16x16x32_bf16(pf[kss], vf, acc_o[o], 0, 0, 0);
            }
        __syncthreads();
    }

    if (NSPLIT == 1) {
        float inv[4];
#pragma unroll
        for (int r = 0; r < 4; r++) inv[r] = 1.0f / l_i[r];
#pragma unroll
        for (int o = 0; o < 8; o++)
#pragma unroll
            for (int r = 0; r < 4; r++) {
                int rowg = batch * T_ + m0 + quad * 4 + r;
                out[(size_t)rowg * H_ + o * 16 + lo] = acc_o[o][r] * inv[r];
            }
    } else {
        // unnormalized partial + (m,l)
        float* Op = Opart + (size_t)split * (16384 * 128);
#pragma unroll
        for (int o = 0; o < 8; o++)
#pragma unroll
            for (int r = 0; r < 4; r++) {
                int rowg = batch * T_ + m0 + quad * 4 + r;
                Op[(size_t)rowg * H_ + o * 16 + lo] = acc_o[o][r];
            }
        if (lo == 0) {
#pragma unroll
            for (int r = 0; r < 4; r++) {
                int rowg = batch * T_ + m0 + quad * 4 + r;
                Mpart[split * 16384 + rowg] = m_i[r];
                Lpart[split * 16384 + rowg] = l_i[r];
            }
        }
    }
}

// ---------------------------------------------------------------------------
// Kernel 4: combine split-KV partials. 8 rows/block, float4 per thread.
// ---------------------------------------------------------------------------
template <int NSPLIT>
__global__ __launch_bounds__(256) void k_comb(const float* __restrict__ Opart,
                                              const float* __restrict__ Mpart,
                                              const float* __restrict__ Lpart,
                                              float* __restrict__ out) {
    int tid = threadIdx.x;
    int row = blockIdx.x * 8 + (tid >> 5);
    int h4 = (tid & 31) * 4;
    float m[NSPLIT], l[NSPLIT];
    float M = -INFINITY;
#pragma unroll
    for (int s = 0; s < NSPLIT; s++) {
        m[s] = Mpart[s * 16384 + row];
        l[s] = Lpart[s * 16384 + row];
        M = fmaxf(M, m[s]);
    }
    float4 o = {0.f, 0.f, 0.f, 0.f};
    float den = 0.f;
#pragma unroll
    for (int s = 0; s < NSPLIT; s++) {
        float w = exp2f(m[s] - M);
        den += w * l[s];
        float4 v = *(const float4*)(Opart + ((size_t)s * 16384 + row) * H_ + h4);
        o.x += w * v.x; o.y += w * v.y; o.z += w * v.z; o.w += w * v.w;
    }
    float inv = 1.0f / den;
    float4 r = {o.x * inv, o.y * inv, o.z * inv, o.w * inv};
    *(float4*)(out + (size_t)row * H_ + h4) = r;
}

// ---------------------------------------------------------------------------
extern "C" void kernel_launch(void* const* d_in, const int* in_sizes, int n_in,
                              void* d_out, int out_size, void* d_ws, size_t ws_size,
                              hipStream_t stream) {
    const float* x  = (const float*)d_in[0];
    const float* Wk = (const float*)d_in[1];
    const float* Wq = (const float*)d_in[2];
    const float* Wv = (const float*)d_in[3];
    char* ws = (char*)d_ws;
    unsigned short* Wt = (unsigned short*)ws;                 // 768 KB
    unsigned short* Qb = (unsigned short*)(ws + (1u << 20));  // 4 MB
    unsigned short* Kb = (unsigned short*)(ws + (5u << 20));  // 4 MB
    unsigned short* Vt = (unsigned short*)(ws + (9u << 20));  // 4 MB -> end 13 MB
    float* out = (float*)d_out;

    const size_t SPLIT_O = (size_t)16384 * 128 * 4;  // 8 MB per split
    const size_t base = (size_t)13 << 20;
    const size_t need4 = base + 4 * SPLIT_O + 8 * 65536;
    const size_t need2 = base + 2 * SPLIT_O + 4 * 65536;

    k_wt  <<<dim3(16, 2, 3), 256, 0, stream>>>(Wk, Wq, Wv, Wt);
    k_qkv <<<dim3(256, 2), 256, 0, stream>>>(x, Wt, Qb, Kb, Vt);

    if (ws_size >= need4) {
        float* Op = (float*)(ws + base);
        float* Mp = (float*)(ws + base + 4 * SPLIT_O);
        float* Lp = (float*)(ws + base + 4 * SPLIT_O + 4 * 65536);
        k_attn<4><<<1024, 256, 0, stream>>>(Qb, Kb, Vt, Op, Mp, Lp, out);
        k_comb<4><<<2048, 256, 0, stream>>>(Op, Mp, Lp, out);
    } else if (ws_size >= need2) {
        float* Op = (float*)(ws + base);
        float* Mp = (float*)(ws + base + 2 * SPLIT_O);
        float* Lp = (float*)(ws + base + 2 * SPLIT_O + 2 * 65536);
        k_attn<2><<<512, 256, 0, stream>>>(Qb, Kb, Vt, Op, Mp, Lp, out);
        k_comb<2><<<2048, 256, 0, stream>>>(Op, Mp, Lp, out);
    } else {
        k_attn<1><<<256, 256, 0, stream>>>(Qb, Kb, Vt, nullptr, nullptr, nullptr, out);
    }
}